// Round 19
// baseline (109.304 us; speedup 1.0000x reference)
//
#include <hip/hip_runtime.h>

#define NPTS   131072
#define CIN    32
#define KPL    2048
#define NLEAF  64
#define NB1    8
#define DPJ    128
#define DHID   256
#define DOUT   512
#define TM     128         // points per block in the leaf kernel
#define KP1    160         // padded K for stage 2' (128 fused + 3 rel + 29 zero)

typedef __attribute__((ext_vector_type(8))) short  short8;
typedef __attribute__((ext_vector_type(4))) float  f32x4;

// round-to-nearest-even f32 -> bf16
__device__ __forceinline__ unsigned short f2bf(float x) {
    unsigned u = __float_as_uint(x);
    u += 0x7FFFu + ((u >> 16) & 1u);
    return (unsigned short)(u >> 16);
}

// ---------------------------------------------------------------------------
// Weight prep + output-zeroing, ONE launch (690 blocks):
//  [0,528): convert wp1t[128][32], we2t[512][256]
//  [528,656): fused Wf = Wp2 @ We1[3:131] -> wft[n][k] bf16 (k per block:
//             scalar Wp2 loads, coalesced We1 loads), stride KP1=160
//  656: bfused
//  657: wft k-rows 128..159: rel rows (We1[0:3]) + zero pad
//  [658,690): zero the 64x512 leaf atomicMax accumulator rows of out
// ---------------------------------------------------------------------------
__global__ __launch_bounds__(256) void prep_weights(
    const float* __restrict__ Wp1, const float* __restrict__ We2,
    const float* __restrict__ Wp2, const float* __restrict__ We1,
    const float* __restrict__ bp2, const float* __restrict__ be1,
    unsigned short* __restrict__ wp1t, unsigned short* __restrict__ we2t,
    unsigned short* __restrict__ wft, float* __restrict__ bfused,
    float* __restrict__ leaf_rows)
{
    const int b = blockIdx.x;
    if (b < 528) {
        int idx = b * 256 + threadIdx.x;
        if (idx < 4096) {                       // Wp1: 32 x 128
            int n = idx / 32, k = idx % 32;
            wp1t[idx] = f2bf(Wp1[k * DPJ + n]);
        } else if (idx < 4096 + 131072) {       // We2: 256 x 512
            int i = idx - 4096;
            int n = i / 256, k = i % 256;
            we2t[i] = f2bf(We2[k * DOUT + n]);
        }
    } else if (b < 656) {
        const int k = b - 528;                  // wave-uniform -> scalar Wp2 loads
        const int n = threadIdx.x;
        float a0 = 0.f, a1 = 0.f, a2 = 0.f, a3 = 0.f;
        #pragma unroll
        for (int j = 0; j < DPJ; j += 4) {
            a0 += Wp2[k * DPJ + j    ] * We1[(3 + j) * DHID + n];
            a1 += Wp2[k * DPJ + j + 1] * We1[(4 + j) * DHID + n];
            a2 += Wp2[k * DPJ + j + 2] * We1[(5 + j) * DHID + n];
            a3 += Wp2[k * DPJ + j + 3] * We1[(6 + j) * DHID + n];
        }
        wft[(size_t)n * KP1 + k] = f2bf((a0 + a1) + (a2 + a3));
    } else if (b == 656) {
        const int n = threadIdx.x;
        float s0 = be1[n], s1 = 0.f, s2 = 0.f, s3 = 0.f;
        #pragma unroll
        for (int j = 0; j < DPJ; j += 4) {
            s0 += bp2[j    ] * We1[(3 + j) * DHID + n];
            s1 += bp2[j + 1] * We1[(4 + j) * DHID + n];
            s2 += bp2[j + 2] * We1[(5 + j) * DHID + n];
            s3 += bp2[j + 3] * We1[(6 + j) * DHID + n];
        }
        bfused[n] = (s0 + s1) + (s2 + s3);
    } else if (b == 657) {
        // wft rows k=128..159: first 3 = We1 rel rows, rest zero
        const int n = threadIdx.x;
        #pragma unroll
        for (int kk = 0; kk < 32; ++kk) {
            unsigned short v = (kk < 3) ? f2bf(We1[kk * DHID + n]) : (unsigned short)0;
            wft[(size_t)n * KP1 + 128 + kk] = v;
        }
    } else {
        int i = (b - 658) * 256 + threadIdx.x;  // 8192 float4 = 32768 floats
        reinterpret_cast<float4*>(leaf_rows)[i] = float4{0.f, 0.f, 0.f, 0.f};
    }
}

// ---------------------------------------------------------------------------
// MFMA GEMM core: acc[MF][NF] (+bias) += A(LDS, swizzled bf16) @ Wt(global, N x K bf16)
// A-frag: row = 16m + (lane&15), k contiguous.  B-frag: col = cb + 16n + (lane&15).
// ---------------------------------------------------------------------------
template<int MF, int NF, int KSTEPS, int SB, int WK>
__device__ __forceinline__ void gemm_core(
    const char* sIn, const unsigned short* __restrict__ wt,
    const float* __restrict__ bias, int cb, int lr, int lg, f32x4 acc[MF][NF])
{
    #pragma unroll
    for (int n = 0; n < NF; ++n) {
        float bv = bias[cb + 16 * n + lr];
        #pragma unroll
        for (int m = 0; m < MF; ++m) acc[m][n] = f32x4{bv, bv, bv, bv};
    }
    #pragma unroll
    for (int kk = 0; kk < KSTEPS; ++kk) {
        short8 b[NF];
        #pragma unroll
        for (int n = 0; n < NF; ++n)
            b[n] = *reinterpret_cast<const short8*>(
                wt + (size_t)(cb + 16 * n + lr) * WK + kk * 32 + lg * 8);
        #pragma unroll
        for (int m = 0; m < MF; ++m) {
            int row  = 16 * m + lr;
            int byte = (row * SB + kk * 64 + lg * 16) ^ ((row & 7) << 4);
            short8 a = *reinterpret_cast<const short8*>(sIn + byte);
            #pragma unroll
            for (int n = 0; n < NF; ++n)
                acc[m][n] = __builtin_amdgcn_mfma_f32_16x16x32_bf16(a, b[n], acc[m][n], 0, 0, 0);
        }
    }
}

// store acc to swizzled bf16 LDS buffer; D mapping row = 16m + lg*4 + r, col = cb+16n+lr
template<int MF, int NF, int SB, bool RELU>
__device__ __forceinline__ void store_frag(char* sOut, int cb, int lr, int lg, f32x4 acc[MF][NF])
{
    #pragma unroll
    for (int m = 0; m < MF; ++m) {
        #pragma unroll
        for (int r = 0; r < 4; ++r) {
            int row = 16 * m + lg * 4 + r;
            int rb  = row * SB;
            int sw  = (row & 7) << 4;
            #pragma unroll
            for (int n = 0; n < NF; ++n) {
                float v = acc[m][n][r];
                if (RELU) v = fmaxf(v, 0.f);
                int byte = (rb + (cb + 16 * n + lr) * 2) ^ sw;
                *reinterpret_cast<unsigned short*>(sOut + byte) = f2bf(v);
            }
        }
    }
}

// max-reduce an acc[MF][NF] block over rows and write to leaf accumulator
template<int MF, int NF>
__device__ __forceinline__ void pool_frag(float* dst, int cb, int lr, int lg, f32x4 acc[MF][NF])
{
    #pragma unroll
    for (int n = 0; n < NF; ++n) {
        float vm = 0.f;   // relu folded into max with 0
        #pragma unroll
        for (int m = 0; m < MF; ++m) {
            #pragma unroll
            for (int r = 0; r < 4; ++r) vm = fmaxf(vm, acc[m][n][r]);
        }
        vm = fmaxf(vm, __shfl_xor(vm, 16));
        vm = fmaxf(vm, __shfl_xor(vm, 32));
        if (lg == 0)
            atomicMax(reinterpret_cast<int*>(dst + cb + 16 * n + lr),
                      __float_as_int(vm));
    }
}

// ---------------------------------------------------------------------------
// Fused per-point pipeline + leaf max-pool, bf16 MFMA.
// grid = NLEAF * (KPL/TM) = 1024 blocks, 256 threads (4 waves, N-split).
//   s1 : P1 = relu(X @ Wp1 + bp1)                 (K=32)
//   s2': H  = relu([P1,rel,0] @ Wf160 + bfused)   (K=160, rel folded via K-pad)
//   s3': out = relu(H @ We2 + be2) -> max-pool    (K=256, SINGLE NF=8 pass)
// R19 change: stage 3' merged from 2x NF=4 passes to 1x NF=8 (acc[8][8] =
// 256 f32/thread). Halves stage-3' A-reads (16->8 ds_read_b128 per K-step),
// one B-latency burst instead of two, single pool pass. Total regs ~350 <
// 450 no-spill bound (m08); occupancy can't drop (1 wave/SIMD, LDS-bound).
// LDS: buf 104 KB { H [0,64K); P1p [64K,104K); X aliased [0,8K) }. 1 block/CU.
// ---------------------------------------------------------------------------
__global__ __launch_bounds__(256, 1) void leaf_mfma_kernel(
    const float* __restrict__ coords, const float* __restrict__ feats,
    const int* __restrict__ leaf_indices, const int* __restrict__ leaf_center_idx,
    const unsigned short* __restrict__ wp1t, const float* __restrict__ bp1,
    const unsigned short* __restrict__ wft, const float* __restrict__ bfused,
    const unsigned short* __restrict__ we2t, const float* __restrict__ be2,
    float* __restrict__ leaf_out)              // = out + (1+NB1)*DOUT, zero-initialized
{
    __shared__ __align__(16) char buf[TM * DHID * 2 + TM * KP1 * 2];  // 64K + 40K

    const int t    = threadIdx.x;
    const int lane = t & 63;
    const int w    = t >> 6;       // wave id 0..3 (N-split)
    const int lr   = lane & 15;
    const int lg   = lane >> 4;

    const int l     = blockIdx.x >> 4;          // leaf (16 chunks/leaf)
    const int chunk = blockIdx.x & 15;
    const int base  = l * KPL + chunk * TM;

    char* const sX   = buf;            // [0, 8K)  (aliased inside H, dead early)
    char* const sH   = buf;            // [0, 64K)
    char* const sP1p = buf + TM * DHID * 2;   // [64K, 104K), row stride 320 B

    // stage features -> bf16 LDS (swizzled): 256 threads, 32B (16 ch) per thread
    {
        const int p  = t >> 1;          // 0..127
        const int kq = (t & 1) << 4;    // 0 or 16
        const int gi = leaf_indices[base + p];
        const float* src = feats + (size_t)gi * CIN + kq;
        float4 v0 = *reinterpret_cast<const float4*>(src);
        float4 v1 = *reinterpret_cast<const float4*>(src + 4);
        float4 v2 = *reinterpret_cast<const float4*>(src + 8);
        float4 v3 = *reinterpret_cast<const float4*>(src + 12);
        short8 o0, o1;
        o0[0] = (short)f2bf(v0.x); o0[1] = (short)f2bf(v0.y);
        o0[2] = (short)f2bf(v0.z); o0[3] = (short)f2bf(v0.w);
        o0[4] = (short)f2bf(v1.x); o0[5] = (short)f2bf(v1.y);
        o0[6] = (short)f2bf(v1.z); o0[7] = (short)f2bf(v1.w);
        o1[0] = (short)f2bf(v2.x); o1[1] = (short)f2bf(v2.y);
        o1[2] = (short)f2bf(v2.z); o1[3] = (short)f2bf(v2.w);
        o1[4] = (short)f2bf(v3.x); o1[5] = (short)f2bf(v3.y);
        o1[6] = (short)f2bf(v3.z); o1[7] = (short)f2bf(v3.w);
        const int sw = (p & 7) << 4;
        int b0 = (p * (CIN * 2) + kq * 2) ^ sw;
        int b1 = (p * (CIN * 2) + kq * 2 + 16) ^ sw;
        *reinterpret_cast<short8*>(sX + b0) = o0;
        *reinterpret_cast<short8*>(sX + b1) = o1;
    }
    // rel -> bf16 into P1p cols 128..130 (+ zero pad cols 131..159), per row
    if (t < TM) {
        const int gi = leaf_indices[base + t];
        const int ci = leaf_center_idx[l];
        short8 relv = short8{0, 0, 0, 0, 0, 0, 0, 0};
        relv[0] = (short)f2bf(coords[gi * 3 + 0] - coords[ci * 3 + 0]);
        relv[1] = (short)f2bf(coords[gi * 3 + 1] - coords[ci * 3 + 1]);
        relv[2] = (short)f2bf(coords[gi * 3 + 2] - coords[ci * 3 + 2]);
        const short8 zero = short8{0, 0, 0, 0, 0, 0, 0, 0};
        const int rb = t * (KP1 * 2);
        const int sw = (t & 7) << 4;
        *reinterpret_cast<short8*>(sP1p + ((rb + 256) ^ sw)) = relv;
        *reinterpret_cast<short8*>(sP1p + ((rb + 272) ^ sw)) = zero;
        *reinterpret_cast<short8*>(sP1p + ((rb + 288) ^ sw)) = zero;
        *reinterpret_cast<short8*>(sP1p + ((rb + 304) ^ sw)) = zero;
    }
    __syncthreads();

    // ---- Stage 1: P1 = relu(X @ Wp1 + bp1)   (128x128, K=32; 32 cols/wave) ----
    {
        f32x4 acc[8][2];
        gemm_core<8, 2, 1, CIN * 2, 32>(sX, wp1t, bp1, w * 32, lr, lg, acc);
        store_frag<8, 2, KP1 * 2, true>(sP1p, w * 32, lr, lg, acc);
    }
    __syncthreads();

    // ---- Stage 2': H = relu([P1,rel,0] @ Wf160 + bfused)  (128x256, K=160; 64 cols/wave) ----
    {
        const int cb = w * 64;
        f32x4 acc[8][4];
        gemm_core<8, 4, 5, KP1 * 2, KP1>(sP1p, wft, bfused, cb, lr, lg, acc);
        store_frag<8, 4, DHID * 2, true>(sH, cb, lr, lg, acc);
    }
    __syncthreads();

    // ---- Stage 3': out = relu(H @ We2 + be2) (128x512, K=256; 128 cols/wave) ----
    // single NF=8 pass (acc[8][8]): A-fragments read once, one B-burst
    {
        float* const dst = leaf_out + (size_t)l * DOUT;
        f32x4 acc[8][8];
        gemm_core<8, 8, 8, DHID * 2, 256>(sH, we2t, be2, w * 128, lr, lg, acc);
        pool_frag<8, 8>(dst, w * 128, lr, lg, acc);
    }
}

// ---------------------------------------------------------------------------
// Aggregator, phase 1 (pool): pooled[p][col] = max_m relu(z_m . Wa1[:,col] + ba1[col])
//   z_m = [child[p*8+m][0:512], coords[child_idx[p*8+m]] - coords[parent_idx[p]]]
// grid = nparent*8 blocks (8 col-chunks of 64), 256 threads (4-way K split).
// ---------------------------------------------------------------------------
__global__ __launch_bounds__(256) void agg_pool_kernel(
    const float* __restrict__ child,      // [nparent*8][512]
    const float* __restrict__ coords,
    const int* __restrict__ child_idx,    // [nparent*8]
    const int* __restrict__ parent_idx,   // [nparent]
    const float* __restrict__ Wa1, const float* __restrict__ ba1,
    float* __restrict__ pooled)           // [nparent][512]
{
    __shared__ float s_z[NB1][516];       // 8 children x (512 feat + 3 rel)
    __shared__ float s_red[4][NB1][64];

    const int t  = threadIdx.x;
    const int b  = blockIdx.x;
    const int p  = b >> 3, cc = b & 7;
    const int c  = t & 63;
    const int col = cc * 64 + c;
    const int ks = t >> 6;                // K-slice 0..3

    {   // stage child features (8 x 512 f32)
        const int m = t >> 5, tt = t & 31;
        const float* src = child + (size_t)(p * NB1 + m) * DOUT;
        #pragma unroll
        for (int i = 0; i < 4; ++i) {
            const int idx = (i * 32 + tt) * 4;
            *reinterpret_cast<float4*>(&s_z[m][idx]) =
                *reinterpret_cast<const float4*>(src + idx);
        }
    }
    if (t < 24) {                         // rel coords into rows 512..514
        const int m = t / 3, j = t % 3;
        s_z[m][512 + j] = coords[child_idx[p * NB1 + m] * 3 + j]
                        - coords[parent_idx[p] * 3 + j];
    }
    __syncthreads();

    float acc[NB1] = {0.f, 0.f, 0.f, 0.f, 0.f, 0.f, 0.f, 0.f};
    const int k0 = ks * 128;
    #pragma unroll 32
    for (int i = 0; i < 128; ++i) {
        const int k = k0 + i;
        const float wv = Wa1[(size_t)k * DOUT + col];
        #pragma unroll
        for (int m = 0; m < NB1; ++m) acc[m] += s_z[m][k] * wv;
    }
    if (ks == 3) {                        // rel rows 512..514
        #pragma unroll
        for (int k = 512; k < 515; ++k) {
            const float wv = Wa1[(size_t)k * DOUT + col];
            #pragma unroll
            for (int m = 0; m < NB1; ++m) acc[m] += s_z[m][k] * wv;
        }
    }
    #pragma unroll
    for (int m = 0; m < NB1; ++m) s_red[ks][m][c] = acc[m];
    __syncthreads();

    if (t < 64) {
        const float bv = ba1[col];
        float pm = 0.f;                   // relu folded into max with 0
        #pragma unroll
        for (int m = 0; m < NB1; ++m) {
            float v = bv + s_red[0][m][c] + s_red[1][m][c]
                         + s_red[2][m][c] + s_red[3][m][c];
            pm = fmaxf(pm, v);
        }
        pooled[(size_t)p * DOUT + col] = pm;
    }
}

// ---------------------------------------------------------------------------
// Aggregator, phase 2 (matvec): outrow[p][col] = pooled[p] . Wa2[:,col] + ba2[col]
// grid = nparent*8 blocks, 256 threads (4-way K split).
// ---------------------------------------------------------------------------
__global__ __launch_bounds__(256) void agg_out_kernel(
    const float* __restrict__ pooled,     // [nparent][512]
    const float* __restrict__ Wa2, const float* __restrict__ ba2,
    float* __restrict__ outbase)          // row p at outbase + p*DOUT
{
    __shared__ float s_p[DOUT];
    __shared__ float s_red[4][64];

    const int t  = threadIdx.x;
    const int b  = blockIdx.x;
    const int p  = b >> 3, cc = b & 7;
    const int c  = t & 63;
    const int col = cc * 64 + c;
    const int ks = t >> 6;

    if (t < 128)
        *reinterpret_cast<float4*>(&s_p[t * 4]) =
            *reinterpret_cast<const float4*>(pooled + (size_t)p * DOUT + t * 4);
    __syncthreads();

    float acc = 0.f;
    const int k0 = ks * 128;
    #pragma unroll 32
    for (int i = 0; i < 128; ++i) {
        const int k = k0 + i;
        acc += s_p[k] * Wa2[(size_t)k * DOUT + col];
    }
    s_red[ks][c] = acc;
    __syncthreads();

    if (t < 64)
        outbase[(size_t)p * DOUT + col] =
            ba2[col] + s_red[0][c] + s_red[1][c] + s_red[2][c] + s_red[3][c];
}

extern "C" void kernel_launch(void* const* d_in, const int* in_sizes, int n_in,
                              void* d_out, int out_size, void* d_ws, size_t ws_size,
                              hipStream_t stream)
{
    const float* coords          = (const float*)d_in[0];
    const float* feats           = (const float*)d_in[1];
    const int*   leaf_indices    = (const int*)d_in[2];
    const int*   leaf_center_idx = (const int*)d_in[3];
    const int*   l1_center_idx   = (const int*)d_in[4];
    const int*   root_center_idx = (const int*)d_in[5];
    const float* Wp1 = (const float*)d_in[6];
    const float* bp1 = (const float*)d_in[7];
    const float* Wp2 = (const float*)d_in[8];
    const float* bp2 = (const float*)d_in[9];
    const float* We1 = (const float*)d_in[10];
    const float* be1 = (const float*)d_in[11];
    const float* We2 = (const float*)d_in[12];
    const float* be2 = (const float*)d_in[13];
    const float* Wa1 = (const float*)d_in[14];
    const float* ba1 = (const float*)d_in[15];
    const float* Wa2 = (const float*)d_in[16];
    const float* ba2 = (const float*)d_in[17];

    float* out = (float*)d_out;
    char*  ws  = (char*)d_ws;
    // ws layout (bytes):
    //   [0,       8192)   wp1t   bf16 128x32
    //   [8192,  270336)   we2t   bf16 512x256
    //   [270336,352256)   wft    bf16 256x160 (fused Wp2@We1[3:] + rel rows + pad)
    //   [352256,353280)   bfused f32 256
    //   [353280,369664)   pooledL1 f32 8x512
    //   [369664,371712)   pooledR  f32 1x512
    unsigned short* wp1t     = (unsigned short*)ws;
    unsigned short* we2t     = (unsigned short*)(ws + 8192);
    unsigned short* wft      = (unsigned short*)(ws + 270336);
    float*          bfused   = (float*)(ws + 352256);
    float*          pooledL1 = (float*)(ws + 353280);
    float*          pooledR  = (float*)(ws + 369664);

    // prep: weight conversion + fusion + zeroing of the leaf atomicMax rows
    prep_weights<<<dim3(690), dim3(256), 0, stream>>>(
        Wp1, We2, Wp2, We1, bp2, be1, wp1t, we2t, wft, bfused,
        out + (size_t)(1 + NB1) * DOUT);

    leaf_mfma_kernel<<<dim3(NLEAF * (KPL / TM)), dim3(256), 0, stream>>>(
        coords, feats, leaf_indices, leaf_center_idx,
        wp1t, bp1, wft, bfused, we2t, be2,
        out + (size_t)(1 + NB1) * DOUT);

    // level 1: 8 parents x 8 leaf children
    agg_pool_kernel<<<dim3(NB1 * 8), dim3(256), 0, stream>>>(
        out + (size_t)(1 + NB1) * DOUT, coords, leaf_center_idx, l1_center_idx,
        Wa1, ba1, pooledL1);
    agg_out_kernel<<<dim3(NB1 * 8), dim3(256), 0, stream>>>(
        pooledL1, Wa2, ba2, out + DOUT);

    // root: 1 parent x 8 level-1 children (reads level-1 rows just written)
    agg_pool_kernel<<<dim3(8), dim3(256), 0, stream>>>(
        out + DOUT, coords, l1_center_idx, root_center_idx,
        Wa1, ba1, pooledR);
    agg_out_kernel<<<dim3(8), dim3(256), 0, stream>>>(
        pooledR, Wa2, ba2, out);
}

// Round 20
// 102.965 us; speedup vs baseline: 1.0616x; 1.0616x over previous
//
#include <hip/hip_runtime.h>

#define NPTS   131072
#define CIN    32
#define KPL    2048
#define NLEAF  64
#define NB1    8
#define DPJ    128
#define DHID   256
#define DOUT   512
#define TM     128         // points per block in the leaf kernel
#define KP1    160         // padded K for stage 2' (128 fused + 3 rel + 29 zero)

typedef __attribute__((ext_vector_type(8))) short  short8;
typedef __attribute__((ext_vector_type(4))) float  f32x4;

// round-to-nearest-even f32 -> bf16
__device__ __forceinline__ unsigned short f2bf(float x) {
    unsigned u = __float_as_uint(x);
    u += 0x7FFFu + ((u >> 16) & 1u);
    return (unsigned short)(u >> 16);
}

// ---------------------------------------------------------------------------
// Weight prep + output-zeroing, ONE launch (690 blocks):
//  [0,528): convert wp1t[128][32], we2t[512][256]
//  [528,656): fused Wf = Wp2 @ We1[3:131] -> wft[n][k] bf16 (k per block:
//             scalar Wp2 loads, coalesced We1 loads), stride KP1=160
//  656: bfused
//  657: wft k-rows 128..159: rel rows (We1[0:3]) + zero pad
//  [658,690): zero the 64x512 leaf atomicMax accumulator rows of out
// ---------------------------------------------------------------------------
__global__ __launch_bounds__(256) void prep_weights(
    const float* __restrict__ Wp1, const float* __restrict__ We2,
    const float* __restrict__ Wp2, const float* __restrict__ We1,
    const float* __restrict__ bp2, const float* __restrict__ be1,
    unsigned short* __restrict__ wp1t, unsigned short* __restrict__ we2t,
    unsigned short* __restrict__ wft, float* __restrict__ bfused,
    float* __restrict__ leaf_rows)
{
    const int b = blockIdx.x;
    if (b < 528) {
        int idx = b * 256 + threadIdx.x;
        if (idx < 4096) {                       // Wp1: 32 x 128
            int n = idx / 32, k = idx % 32;
            wp1t[idx] = f2bf(Wp1[k * DPJ + n]);
        } else if (idx < 4096 + 131072) {       // We2: 256 x 512
            int i = idx - 4096;
            int n = i / 256, k = i % 256;
            we2t[i] = f2bf(We2[k * DOUT + n]);
        }
    } else if (b < 656) {
        const int k = b - 528;                  // wave-uniform -> scalar Wp2 loads
        const int n = threadIdx.x;
        float a0 = 0.f, a1 = 0.f, a2 = 0.f, a3 = 0.f;
        #pragma unroll
        for (int j = 0; j < DPJ; j += 4) {
            a0 += Wp2[k * DPJ + j    ] * We1[(3 + j) * DHID + n];
            a1 += Wp2[k * DPJ + j + 1] * We1[(4 + j) * DHID + n];
            a2 += Wp2[k * DPJ + j + 2] * We1[(5 + j) * DHID + n];
            a3 += Wp2[k * DPJ + j + 3] * We1[(6 + j) * DHID + n];
        }
        wft[(size_t)n * KP1 + k] = f2bf((a0 + a1) + (a2 + a3));
    } else if (b == 656) {
        const int n = threadIdx.x;
        float s0 = be1[n], s1 = 0.f, s2 = 0.f, s3 = 0.f;
        #pragma unroll
        for (int j = 0; j < DPJ; j += 4) {
            s0 += bp2[j    ] * We1[(3 + j) * DHID + n];
            s1 += bp2[j + 1] * We1[(4 + j) * DHID + n];
            s2 += bp2[j + 2] * We1[(5 + j) * DHID + n];
            s3 += bp2[j + 3] * We1[(6 + j) * DHID + n];
        }
        bfused[n] = (s0 + s1) + (s2 + s3);
    } else if (b == 657) {
        // wft rows k=128..159: first 3 = We1 rel rows, rest zero
        const int n = threadIdx.x;
        #pragma unroll
        for (int kk = 0; kk < 32; ++kk) {
            unsigned short v = (kk < 3) ? f2bf(We1[kk * DHID + n]) : (unsigned short)0;
            wft[(size_t)n * KP1 + 128 + kk] = v;
        }
    } else {
        int i = (b - 658) * 256 + threadIdx.x;  // 8192 float4 = 32768 floats
        reinterpret_cast<float4*>(leaf_rows)[i] = float4{0.f, 0.f, 0.f, 0.f};
    }
}

// ---------------------------------------------------------------------------
// MFMA GEMM core: acc[MF][NF] (+bias) += A(LDS, swizzled bf16) @ Wt(global, N x K bf16)
// A-frag: row = 16m + (lane&15), k contiguous.  B-frag: col = cb + 16n + (lane&15).
// ---------------------------------------------------------------------------
template<int MF, int NF, int KSTEPS, int SB, int WK>
__device__ __forceinline__ void gemm_core(
    const char* sIn, const unsigned short* __restrict__ wt,
    const float* __restrict__ bias, int cb, int lr, int lg, f32x4 acc[MF][NF])
{
    #pragma unroll
    for (int n = 0; n < NF; ++n) {
        float bv = bias[cb + 16 * n + lr];
        #pragma unroll
        for (int m = 0; m < MF; ++m) acc[m][n] = f32x4{bv, bv, bv, bv};
    }
    #pragma unroll
    for (int kk = 0; kk < KSTEPS; ++kk) {
        short8 b[NF];
        #pragma unroll
        for (int n = 0; n < NF; ++n)
            b[n] = *reinterpret_cast<const short8*>(
                wt + (size_t)(cb + 16 * n + lr) * WK + kk * 32 + lg * 8);
        #pragma unroll
        for (int m = 0; m < MF; ++m) {
            int row  = 16 * m + lr;
            int byte = (row * SB + kk * 64 + lg * 16) ^ ((row & 7) << 4);
            short8 a = *reinterpret_cast<const short8*>(sIn + byte);
            #pragma unroll
            for (int n = 0; n < NF; ++n)
                acc[m][n] = __builtin_amdgcn_mfma_f32_16x16x32_bf16(a, b[n], acc[m][n], 0, 0, 0);
        }
    }
}

// store acc to swizzled bf16 LDS buffer; D mapping row = 16m + lg*4 + r, col = cb+16n+lr
template<int MF, int NF, int SB, bool RELU>
__device__ __forceinline__ void store_frag(char* sOut, int cb, int lr, int lg, f32x4 acc[MF][NF])
{
    #pragma unroll
    for (int m = 0; m < MF; ++m) {
        #pragma unroll
        for (int r = 0; r < 4; ++r) {
            int row = 16 * m + lg * 4 + r;
            int rb  = row * SB;
            int sw  = (row & 7) << 4;
            #pragma unroll
            for (int n = 0; n < NF; ++n) {
                float v = acc[m][n][r];
                if (RELU) v = fmaxf(v, 0.f);
                int byte = (rb + (cb + 16 * n + lr) * 2) ^ sw;
                *reinterpret_cast<unsigned short*>(sOut + byte) = f2bf(v);
            }
        }
    }
}

// max-reduce an acc[MF][NF] block over rows and write to leaf accumulator
template<int MF, int NF>
__device__ __forceinline__ void pool_frag(float* dst, int cb, int lr, int lg, f32x4 acc[MF][NF])
{
    #pragma unroll
    for (int n = 0; n < NF; ++n) {
        float vm = 0.f;   // relu folded into max with 0
        #pragma unroll
        for (int m = 0; m < MF; ++m) {
            #pragma unroll
            for (int r = 0; r < 4; ++r) vm = fmaxf(vm, acc[m][n][r]);
        }
        vm = fmaxf(vm, __shfl_xor(vm, 16));
        vm = fmaxf(vm, __shfl_xor(vm, 32));
        if (lg == 0)
            atomicMax(reinterpret_cast<int*>(dst + cb + 16 * n + lr),
                      __float_as_int(vm));
    }
}

// ---------------------------------------------------------------------------
// Fused per-point pipeline + leaf max-pool, bf16 MFMA.  (R18-verified config:
// leaf ~81 us, 244 VGPR, no spill — session best.)
// grid = NLEAF * (KPL/TM) = 1024 blocks, 256 threads (4 waves, N-split).
//   s1 : P1 = relu(X @ Wp1 + bp1)                 (K=32)
//   s2': H  = relu([P1,rel,0] @ Wf160 + bfused)   (K=160, rel folded via K-pad)
//   s3': out = relu(H @ We2 + be2) -> max-pool    (K=256, TWO NF=4 passes)
// NOTE: stage-3' stays 2x NF=4 (acc 128). R19's single NF=8 pass (acc 256)
// regressed 8%: the allocator sacrificed scheduling registers (VGPR 244->192)
// for the accumulators, serializing the load pipeline. acc[8][4] is the
// sweet spot between fragment reuse and scheduling freedom.
// LDS: buf 104 KB { H [0,64K); P1p [64K,104K); X aliased [0,8K) }. 1 block/CU.
// ---------------------------------------------------------------------------
__global__ __launch_bounds__(256, 1) void leaf_mfma_kernel(
    const float* __restrict__ coords, const float* __restrict__ feats,
    const int* __restrict__ leaf_indices, const int* __restrict__ leaf_center_idx,
    const unsigned short* __restrict__ wp1t, const float* __restrict__ bp1,
    const unsigned short* __restrict__ wft, const float* __restrict__ bfused,
    const unsigned short* __restrict__ we2t, const float* __restrict__ be2,
    float* __restrict__ leaf_out)              // = out + (1+NB1)*DOUT, zero-initialized
{
    __shared__ __align__(16) char buf[TM * DHID * 2 + TM * KP1 * 2];  // 64K + 40K

    const int t    = threadIdx.x;
    const int lane = t & 63;
    const int w    = t >> 6;       // wave id 0..3 (N-split)
    const int lr   = lane & 15;
    const int lg   = lane >> 4;

    const int l     = blockIdx.x >> 4;          // leaf (16 chunks/leaf)
    const int chunk = blockIdx.x & 15;
    const int base  = l * KPL + chunk * TM;

    char* const sX   = buf;            // [0, 8K)  (aliased inside H, dead early)
    char* const sH   = buf;            // [0, 64K)
    char* const sP1p = buf + TM * DHID * 2;   // [64K, 104K), row stride 320 B

    // stage features -> bf16 LDS (swizzled): 256 threads, 32B (16 ch) per thread
    {
        const int p  = t >> 1;          // 0..127
        const int kq = (t & 1) << 4;    // 0 or 16
        const int gi = leaf_indices[base + p];
        const float* src = feats + (size_t)gi * CIN + kq;
        float4 v0 = *reinterpret_cast<const float4*>(src);
        float4 v1 = *reinterpret_cast<const float4*>(src + 4);
        float4 v2 = *reinterpret_cast<const float4*>(src + 8);
        float4 v3 = *reinterpret_cast<const float4*>(src + 12);
        short8 o0, o1;
        o0[0] = (short)f2bf(v0.x); o0[1] = (short)f2bf(v0.y);
        o0[2] = (short)f2bf(v0.z); o0[3] = (short)f2bf(v0.w);
        o0[4] = (short)f2bf(v1.x); o0[5] = (short)f2bf(v1.y);
        o0[6] = (short)f2bf(v1.z); o0[7] = (short)f2bf(v1.w);
        o1[0] = (short)f2bf(v2.x); o1[1] = (short)f2bf(v2.y);
        o1[2] = (short)f2bf(v2.z); o1[3] = (short)f2bf(v2.w);
        o1[4] = (short)f2bf(v3.x); o1[5] = (short)f2bf(v3.y);
        o1[6] = (short)f2bf(v3.z); o1[7] = (short)f2bf(v3.w);
        const int sw = (p & 7) << 4;
        int b0 = (p * (CIN * 2) + kq * 2) ^ sw;
        int b1 = (p * (CIN * 2) + kq * 2 + 16) ^ sw;
        *reinterpret_cast<short8*>(sX + b0) = o0;
        *reinterpret_cast<short8*>(sX + b1) = o1;
    }
    // rel -> bf16 into P1p cols 128..130 (+ zero pad cols 131..159), per row
    if (t < TM) {
        const int gi = leaf_indices[base + t];
        const int ci = leaf_center_idx[l];
        short8 relv = short8{0, 0, 0, 0, 0, 0, 0, 0};
        relv[0] = (short)f2bf(coords[gi * 3 + 0] - coords[ci * 3 + 0]);
        relv[1] = (short)f2bf(coords[gi * 3 + 1] - coords[ci * 3 + 1]);
        relv[2] = (short)f2bf(coords[gi * 3 + 2] - coords[ci * 3 + 2]);
        const short8 zero = short8{0, 0, 0, 0, 0, 0, 0, 0};
        const int rb = t * (KP1 * 2);
        const int sw = (t & 7) << 4;
        *reinterpret_cast<short8*>(sP1p + ((rb + 256) ^ sw)) = relv;
        *reinterpret_cast<short8*>(sP1p + ((rb + 272) ^ sw)) = zero;
        *reinterpret_cast<short8*>(sP1p + ((rb + 288) ^ sw)) = zero;
        *reinterpret_cast<short8*>(sP1p + ((rb + 304) ^ sw)) = zero;
    }
    __syncthreads();

    // ---- Stage 1: P1 = relu(X @ Wp1 + bp1)   (128x128, K=32; 32 cols/wave) ----
    {
        f32x4 acc[8][2];
        gemm_core<8, 2, 1, CIN * 2, 32>(sX, wp1t, bp1, w * 32, lr, lg, acc);
        store_frag<8, 2, KP1 * 2, true>(sP1p, w * 32, lr, lg, acc);
    }
    __syncthreads();

    // ---- Stage 2': H = relu([P1,rel,0] @ Wf160 + bfused)  (128x256, K=160; 64 cols/wave) ----
    {
        const int cb = w * 64;
        f32x4 acc[8][4];
        gemm_core<8, 4, 5, KP1 * 2, KP1>(sP1p, wft, bfused, cb, lr, lg, acc);
        store_frag<8, 4, DHID * 2, true>(sH, cb, lr, lg, acc);
    }
    __syncthreads();

    // ---- Stage 3': out = relu(H @ We2 + be2) (128x512, K=256; 128 cols/wave) ----
    // two passes of NF=4 (acc 128) — verified register shape
    {
        float* const dst = leaf_out + (size_t)l * DOUT;
        #pragma unroll
        for (int p4 = 0; p4 < 2; ++p4) {
            const int cb = w * 128 + p4 * 64;
            f32x4 acc[8][4];
            gemm_core<8, 4, 8, DHID * 2, 256>(sH, we2t, be2, cb, lr, lg, acc);
            pool_frag<8, 4>(dst, cb, lr, lg, acc);
        }
    }
}

// ---------------------------------------------------------------------------
// Aggregator, phase 1 (pool): pooled[p][col] = max_m relu(z_m . Wa1[:,col] + ba1[col])
//   z_m = [child[p*8+m][0:512], coords[child_idx[p*8+m]] - coords[parent_idx[p]]]
// grid = nparent*8 blocks (8 col-chunks of 64), 256 threads (4-way K split).
// ---------------------------------------------------------------------------
__global__ __launch_bounds__(256) void agg_pool_kernel(
    const float* __restrict__ child,      // [nparent*8][512]
    const float* __restrict__ coords,
    const int* __restrict__ child_idx,    // [nparent*8]
    const int* __restrict__ parent_idx,   // [nparent]
    const float* __restrict__ Wa1, const float* __restrict__ ba1,
    float* __restrict__ pooled)           // [nparent][512]
{
    __shared__ float s_z[NB1][516];       // 8 children x (512 feat + 3 rel)
    __shared__ float s_red[4][NB1][64];

    const int t  = threadIdx.x;
    const int b  = blockIdx.x;
    const int p  = b >> 3, cc = b & 7;
    const int c  = t & 63;
    const int col = cc * 64 + c;
    const int ks = t >> 6;                // K-slice 0..3

    {   // stage child features (8 x 512 f32)
        const int m = t >> 5, tt = t & 31;
        const float* src = child + (size_t)(p * NB1 + m) * DOUT;
        #pragma unroll
        for (int i = 0; i < 4; ++i) {
            const int idx = (i * 32 + tt) * 4;
            *reinterpret_cast<float4*>(&s_z[m][idx]) =
                *reinterpret_cast<const float4*>(src + idx);
        }
    }
    if (t < 24) {                         // rel coords into rows 512..514
        const int m = t / 3, j = t % 3;
        s_z[m][512 + j] = coords[child_idx[p * NB1 + m] * 3 + j]
                        - coords[parent_idx[p] * 3 + j];
    }
    __syncthreads();

    float acc[NB1] = {0.f, 0.f, 0.f, 0.f, 0.f, 0.f, 0.f, 0.f};
    const int k0 = ks * 128;
    #pragma unroll 32
    for (int i = 0; i < 128; ++i) {
        const int k = k0 + i;
        const float wv = Wa1[(size_t)k * DOUT + col];
        #pragma unroll
        for (int m = 0; m < NB1; ++m) acc[m] += s_z[m][k] * wv;
    }
    if (ks == 3) {                        // rel rows 512..514
        #pragma unroll
        for (int k = 512; k < 515; ++k) {
            const float wv = Wa1[(size_t)k * DOUT + col];
            #pragma unroll
            for (int m = 0; m < NB1; ++m) acc[m] += s_z[m][k] * wv;
        }
    }
    #pragma unroll
    for (int m = 0; m < NB1; ++m) s_red[ks][m][c] = acc[m];
    __syncthreads();

    if (t < 64) {
        const float bv = ba1[col];
        float pm = 0.f;                   // relu folded into max with 0
        #pragma unroll
        for (int m = 0; m < NB1; ++m) {
            float v = bv + s_red[0][m][c] + s_red[1][m][c]
                         + s_red[2][m][c] + s_red[3][m][c];
            pm = fmaxf(pm, v);
        }
        pooled[(size_t)p * DOUT + col] = pm;
    }
}

// ---------------------------------------------------------------------------
// Aggregator, phase 2 (matvec): outrow[p][col] = pooled[p] . Wa2[:,col] + ba2[col]
// grid = nparent*8 blocks, 256 threads (4-way K split).
// ---------------------------------------------------------------------------
__global__ __launch_bounds__(256) void agg_out_kernel(
    const float* __restrict__ pooled,     // [nparent][512]
    const float* __restrict__ Wa2, const float* __restrict__ ba2,
    float* __restrict__ outbase)          // row p at outbase + p*DOUT
{
    __shared__ float s_p[DOUT];
    __shared__ float s_red[4][64];

    const int t  = threadIdx.x;
    const int b  = blockIdx.x;
    const int p  = b >> 3, cc = b & 7;
    const int c  = t & 63;
    const int col = cc * 64 + c;
    const int ks = t >> 6;

    if (t < 128)
        *reinterpret_cast<float4*>(&s_p[t * 4]) =
            *reinterpret_cast<const float4*>(pooled + (size_t)p * DOUT + t * 4);
    __syncthreads();

    float acc = 0.f;
    const int k0 = ks * 128;
    #pragma unroll 32
    for (int i = 0; i < 128; ++i) {
        const int k = k0 + i;
        acc += s_p[k] * Wa2[(size_t)k * DOUT + col];
    }
    s_red[ks][c] = acc;
    __syncthreads();

    if (t < 64)
        outbase[(size_t)p * DOUT + col] =
            ba2[col] + s_red[0][c] + s_red[1][c] + s_red[2][c] + s_red[3][c];
}

extern "C" void kernel_launch(void* const* d_in, const int* in_sizes, int n_in,
                              void* d_out, int out_size, void* d_ws, size_t ws_size,
                              hipStream_t stream)
{
    const float* coords          = (const float*)d_in[0];
    const float* feats           = (const float*)d_in[1];
    const int*   leaf_indices    = (const int*)d_in[2];
    const int*   leaf_center_idx = (const int*)d_in[3];
    const int*   l1_center_idx   = (const int*)d_in[4];
    const int*   root_center_idx = (const int*)d_in[5];
    const float* Wp1 = (const float*)d_in[6];
    const float* bp1 = (const float*)d_in[7];
    const float* Wp2 = (const float*)d_in[8];
    const float* bp2 = (const float*)d_in[9];
    const float* We1 = (const float*)d_in[10];
    const float* be1 = (const float*)d_in[11];
    const float* We2 = (const float*)d_in[12];
    const float* be2 = (const float*)d_in[13];
    const float* Wa1 = (const float*)d_in[14];
    const float* ba1 = (const float*)d_in[15];
    const float* Wa2 = (const float*)d_in[16];
    const float* ba2 = (const float*)d_in[17];

    float* out = (float*)d_out;
    char*  ws  = (char*)d_ws;
    // ws layout (bytes):
    //   [0,       8192)   wp1t   bf16 128x32
    //   [8192,  270336)   we2t   bf16 512x256
    //   [270336,352256)   wft    bf16 256x160 (fused Wp2@We1[3:] + rel rows + pad)
    //   [352256,353280)   bfused f32 256
    //   [353280,369664)   pooledL1 f32 8x512
    //   [369664,371712)   pooledR  f32 1x512
    unsigned short* wp1t     = (unsigned short*)ws;
    unsigned short* we2t     = (unsigned short*)(ws + 8192);
    unsigned short* wft      = (unsigned short*)(ws + 270336);
    float*          bfused   = (float*)(ws + 352256);
    float*          pooledL1 = (float*)(ws + 353280);
    float*          pooledR  = (float*)(ws + 369664);

    // prep: weight conversion + fusion + zeroing of the leaf atomicMax rows
    prep_weights<<<dim3(690), dim3(256), 0, stream>>>(
        Wp1, We2, Wp2, We1, bp2, be1, wp1t, we2t, wft, bfused,
        out + (size_t)(1 + NB1) * DOUT);

    leaf_mfma_kernel<<<dim3(NLEAF * (KPL / TM)), dim3(256), 0, stream>>>(
        coords, feats, leaf_indices, leaf_center_idx,
        wp1t, bp1, wft, bfused, we2t, be2,
        out + (size_t)(1 + NB1) * DOUT);

    // level 1: 8 parents x 8 leaf children
    agg_pool_kernel<<<dim3(NB1 * 8), dim3(256), 0, stream>>>(
        out + (size_t)(1 + NB1) * DOUT, coords, leaf_center_idx, l1_center_idx,
        Wa1, ba1, pooledL1);
    agg_out_kernel<<<dim3(NB1 * 8), dim3(256), 0, stream>>>(
        pooledL1, Wa2, ba2, out + DOUT);

    // root: 1 parent x 8 level-1 children (reads level-1 rows just written)
    agg_pool_kernel<<<dim3(8), dim3(256), 0, stream>>>(
        out + DOUT, coords, l1_center_idx, root_center_idx,
        Wa1, ba1, pooledR);
    agg_out_kernel<<<dim3(8), dim3(256), 0, stream>>>(
        pooledR, Wa2, ba2, out);
}